// Round 6
// baseline (1563.286 us; speedup 1.0000x reference)
//
#include <hip/hip_runtime.h>

#define N_    64
#define HW_   240
#define H1_   120
#define H2_   60
#define C0_   3
#define C1_   32
#define C2_   64
#define C3_   128
#define HEAD_ 1280

typedef unsigned short US;
typedef short bf16x8 __attribute__((ext_vector_type(8)));
typedef float f32x16 __attribute__((ext_vector_type(16)));

__device__ __forceinline__ US f2bf(float f) {
  union { float f; unsigned u; } v; v.f = f;
  unsigned r = v.u + 0x7FFF + ((v.u >> 16) & 1);  // RNE
  return (US)(r >> 16);
}

// h1p padded NHWC: [n][122][122][32] bf16. interior pixel (y,x) -> [y+1][x+1].
#define H1P_ROW   (122 * 32)

// ---------------------------------------------------------------------------
// K0: prep — zero h1p pad cells; convert w1 -> wt1 [ky][oc][kx*32+ic] bf16;
// convert w2 -> wt2 [oc][ic] bf16.
// ---------------------------------------------------------------------------
#define PADN  15488           // pad elems per n
#define PADT  (64 * PADN)     // 991232
__global__ __launch_bounds__(256) void k0_prep(
    const float* __restrict__ w1, const float* __restrict__ w2,
    US* __restrict__ h1p, US* __restrict__ wt1, US* __restrict__ wt2) {
  int gid = blockIdx.x * 256 + threadIdx.x;
  if (gid < PADT) {
    int n = gid / PADN, q = gid % PADN;
    int y, x, ic;
    if (q < 7808) {            // rows 0 and 121, full width
      y = (q < 3904) ? 0 : 121;
      int r = q % 3904; x = r >> 5; ic = r & 31;
    } else {                   // cols 0 and 121, y 1..120
      int q2 = q - 7808;
      x = (q2 < 3840) ? 0 : 121;
      int r = q2 % 3840; y = 1 + (r >> 5); ic = r & 31;
    }
    h1p[(((long)n * 122 + y) * 122 + x) * 32 + ic] = 0;
  } else if (gid < PADT + 18432) {
    int e = gid - PADT;                       // w1 flat [oc][ic][ky][kx]
    int oc = e / 288, ic = (e / 9) % 32, ky = (e / 3) % 3, kx = e % 3;
    wt1[(ky * 64 + oc) * 96 + kx * 32 + ic] = f2bf(w1[e]);
  } else if (gid < PADT + 18432 + 8192) {
    int e = gid - (PADT + 18432);
    wt2[e] = f2bf(w2[e]);
  }
}

// ---------------------------------------------------------------------------
// K1: stem conv 3->32, 3x3 s2 p1, fused BN+ReLU; f32 vector math, writes
// padded NHWC bf16. Thread: 32 oc x 4 px, computed as TWO sequential 2-px
// iterations so only 64 f32 accumulators are live (fits real VGPRs; avoids
// AGPR accvgpr_read/write shuffling seen at 128 live accs).
// Block: 128 threads = 4 rows x 32 slots (30 active). Grid (30, 64).
// ---------------------------------------------------------------------------
__global__ __launch_bounds__(128) void k1_stem(
    const float* __restrict__ x, const float* __restrict__ w,
    const float* __restrict__ alpha, const float* __restrict__ beta,
    US* __restrict__ h1p) {
  __shared__ float wl[C1_ * C0_ * 3 * 4];  // [oc][ic][ky][kx pad4] 1152 f
  int n = blockIdx.y;
  for (int e = threadIdx.x; e < C1_ * 27; e += 128) {
    int oc = e / 27, rem = e % 27;
    int ic = rem / 9, ky = (rem / 3) % 3, kx = rem % 3;
    wl[((oc * C0_ + ic) * 3 + ky) * 4 + kx] = w[e];
  }
  __syncthreads();
  int t = threadIdx.x;
  int xg = t & 31, r = t >> 5;
  if (xg >= 30) return;
  int y = blockIdx.x * 4 + r;          // 30*4 = 120 exact
  int iy0 = 2 * y - 1;

  int rofs[3]; bool yok[3];
#pragma unroll
  for (int ky = 0; ky < 3; ky++) {
    int iy = iy0 + ky;
    yok[ky] = (iy >= 0);               // upper bound never exceeded
    rofs[ky] = (iy < 0 ? 0 : iy) * HW_;
  }

  const float* xn = x + (long)n * C0_ * HW_ * HW_;
  long obase = (((long)n * 122 + (y + 1)) * 122 + 1) * 32;

#pragma unroll
  for (int p2 = 0; p2 < 2; p2++) {
    int x0 = 4 * xg + 2 * p2;          // first px of this pair
    int ixA = 2 * x0;                  // 16B-aligned float4 base
    bool left = (x0 == 0);
    int ixSm = left ? 0 : (ixA - 1);

    float acc[C1_][2];
#pragma unroll
    for (int o = 0; o < C1_; o++) { acc[o][0] = 0.f; acc[o][1] = 0.f; }

#pragma unroll
    for (int ic = 0; ic < C0_; ic++) {
      const float* xc = xn + ic * HW_ * HW_;
#pragma unroll
      for (int ky = 0; ky < 3; ky++) {
        const float* row = xc + rofs[ky];
        float  s0 = row[ixSm];
        float4 va = *(const float4*)(row + ixA);
        bool ym = yok[ky];
        float w0 = (ym && !left) ? s0 : 0.f;
        float w1 = ym ? va.x : 0.f;
        float w2 = ym ? va.y : 0.f;
        float w3 = ym ? va.z : 0.f;
        float w4 = ym ? va.w : 0.f;
#pragma unroll
        for (int oc = 0; oc < C1_; oc++) {
          float4 wv = *(const float4*)(wl + ((oc * C0_ + ic) * 3 + ky) * 4);
          acc[oc][0] = fmaf(w0, wv.x, acc[oc][0]);
          acc[oc][0] = fmaf(w1, wv.y, acc[oc][0]);
          acc[oc][0] = fmaf(w2, wv.z, acc[oc][0]);
          acc[oc][1] = fmaf(w2, wv.x, acc[oc][1]);
          acc[oc][1] = fmaf(w3, wv.y, acc[oc][1]);
          acc[oc][1] = fmaf(w4, wv.z, acc[oc][1]);
        }
      }
    }
    // epilogue: BN + ReLU + bf16 pack + store 2 px * 64 B
#pragma unroll
    for (int p = 0; p < 2; p++) {
      long pbase = obase + (long)(x0 + p) * 32;
#pragma unroll
      for (int g = 0; g < 4; g++) {
        unsigned q[4];
#pragma unroll
        for (int k = 0; k < 4; k++) {
          int o = g * 8 + 2 * k;
          float v0 = fmaxf(fmaf(acc[o][p],     alpha[o],     beta[o]),     0.f);
          float v1 = fmaxf(fmaf(acc[o + 1][p], alpha[o + 1], beta[o + 1]), 0.f);
          q[k] = (unsigned)f2bf(v0) | ((unsigned)f2bf(v1) << 16);
        }
        uint4 u; u.x = q[0]; u.y = q[1]; u.z = q[2]; u.w = q[3];
        *(uint4*)(h1p + pbase + g * 8) = u;
      }
    }
  }
}

// ---------------------------------------------------------------------------
// K2: conv 32->64 3x3 s2 via implicit-GEMM MFMA (bf16 in, f32 acc).
// Block 64px x 64oc, 4 waves (2x2). K = 3 ky-slabs of 96 contiguous (kx,ic).
// A from global h1p (NHWC, padded -> no masks); B from global wt1.
// Grid (57, 64).
// ---------------------------------------------------------------------------
__global__ __launch_bounds__(256) void k2_mfma(
    const US* __restrict__ h1p, const US* __restrict__ wt1,
    const float* __restrict__ alpha, const float* __restrict__ beta,
    US* __restrict__ h2p) {
  int n = blockIdx.y, tile = blockIdx.x;
  int t = threadIdx.x, w = t >> 6, l = t & 63;
  int wm = w & 1, wn = w >> 1;
  int pxb = tile * 64 + wm * 32;
  int lane31 = l & 31, half = l >> 5;
  int p = pxb + lane31; int pc = p < 3600 ? p : 3599;
  int y = pc / 60, xx = pc % 60;
  long abase = (((long)n * 122 + 2 * y) * 122 + 2 * xx) * 32 + half * 8;
  int oc = wn * 32 + lane31;
  const US* bbase = wt1 + oc * 96 + half * 8;

  f32x16 acc;
#pragma unroll
  for (int i = 0; i < 16; i++) acc[i] = 0.f;

#pragma unroll
  for (int ky = 0; ky < 3; ky++) {
    const US* aptr = h1p + abase + ky * H1P_ROW;
    const US* bptr = bbase + ky * (64 * 96);
#pragma unroll
    for (int s = 0; s < 6; s++) {
      bf16x8 av = *(const bf16x8*)(aptr + s * 16);
      bf16x8 bv = *(const bf16x8*)(bptr + s * 16);
      acc = __builtin_amdgcn_mfma_f32_32x32x16_bf16(av, bv, acc, 0, 0, 0);
    }
  }
  float al = alpha[oc], be = beta[oc];
  US* out = h2p + (long)n * 3600 * 64 + oc;
#pragma unroll
  for (int r = 0; r < 16; r++) {
    int row = (r & 3) + 8 * (r >> 2) + 4 * half;
    int pp = pxb + row;
    if (pp < 3600) {
      float v = fmaxf(fmaf(acc[r], al, be), 0.f);
      out[(long)pp * 64] = f2bf(v);
    }
  }
}

// ---------------------------------------------------------------------------
// K3: pointwise 64->128 + BN + ReLU + GAP via MFMA. Wave w owns oc-tile
// 32w..32w+31; loops px tiles of 32; per-lane running sum; shfl_xor(32)
// combines halves; one atomic per oc. Grid (15, 64).
// ---------------------------------------------------------------------------
__global__ __launch_bounds__(256) void k3_mfma(
    const US* __restrict__ h2p, const US* __restrict__ wt2,
    const float* __restrict__ alpha, const float* __restrict__ beta,
    float* __restrict__ gap) {
  int n = blockIdx.y, chunk = blockIdx.x;
  int t = threadIdx.x, w = t >> 6, l = t & 63;
  int lane31 = l & 31, half = l >> 5;
  int oc = w * 32 + lane31;
  float al = alpha[oc], be = beta[oc];
  const US* bbase = wt2 + oc * 64 + half * 8;
  int t0 = chunk * 8, t1 = t0 + 8;
  if (t1 > 113) t1 = 113;
  const US* h2n = h2p + (long)n * 3600 * 64;
  float s = 0.f;
  for (int tile = t0; tile < t1; tile++) {
    int p0 = tile * 32;
    int p = p0 + lane31; int pc = p < 3600 ? p : 3599;
    const US* aptr = h2n + (long)pc * 64 + half * 8;
    f32x16 acc;
#pragma unroll
    for (int i = 0; i < 16; i++) acc[i] = 0.f;
#pragma unroll
    for (int s4 = 0; s4 < 4; s4++) {
      bf16x8 av = *(const bf16x8*)(aptr + s4 * 16);
      bf16x8 bv = *(const bf16x8*)(bbase + s4 * 16);
      acc = __builtin_amdgcn_mfma_f32_32x32x16_bf16(av, bv, acc, 0, 0, 0);
    }
    if (p0 + 31 < 3600) {
#pragma unroll
      for (int r = 0; r < 16; r++) s += fmaxf(fmaf(acc[r], al, be), 0.f);
    } else {
#pragma unroll
      for (int r = 0; r < 16; r++) {
        int row = (r & 3) + 8 * (r >> 2) + 4 * half;
        if (p0 + row < 3600) s += fmaxf(fmaf(acc[r], al, be), 0.f);
      }
    }
  }
  s += __shfl_xor(s, 32);
  if (half == 0) atomicAdd(gap + n * C3_ + oc, s);
}

// ---------------------------------------------------------------------------
// K4: head — gap/3600 @ w_head^T, BN fold + ReLU (f32).
// ---------------------------------------------------------------------------
__global__ __launch_bounds__(256) void k4_head(
    const float* __restrict__ gap, const float* __restrict__ wh,
    const float* __restrict__ alpha, const float* __restrict__ beta,
    float* __restrict__ out) {
  __shared__ float g[C3_];
  int n = blockIdx.y;
  int o = blockIdx.x * 256 + threadIdx.x;
  if (threadIdx.x < C3_)
    g[threadIdx.x] = gap[n * C3_ + threadIdx.x] * (1.f / 3600.f);
  __syncthreads();
  const float* wr = wh + (long)o * C3_;
  float acc = 0.f;
#pragma unroll 8
  for (int c = 0; c < C3_; c += 4) {
    float4 wv = *(const float4*)(wr + c);
    acc = fmaf(wv.x, g[c],     acc);
    acc = fmaf(wv.y, g[c + 1], acc);
    acc = fmaf(wv.z, g[c + 2], acc);
    acc = fmaf(wv.w, g[c + 3], acc);
  }
  out[n * HEAD_ + o] = fmaxf(fmaf(acc, alpha[o], beta[o]), 0.f);
}

// ---------------------------------------------------------------------------
extern "C" void kernel_launch(void* const* d_in, const int* in_sizes, int n_in,
                              void* d_out, int out_size, void* d_ws,
                              size_t ws_size, hipStream_t stream) {
  const float* x      = (const float*)d_in[0];
  const float* w_stem = (const float*)d_in[1];
  const float* a_stem = (const float*)d_in[2];
  const float* b_stem = (const float*)d_in[3];
  const float* w1     = (const float*)d_in[4];
  const float* a1     = (const float*)d_in[5];
  const float* b1     = (const float*)d_in[6];
  const float* w2     = (const float*)d_in[7];
  const float* a2     = (const float*)d_in[8];
  const float* b2     = (const float*)d_in[9];
  const float* wh     = (const float*)d_in[10];
  const float* ah     = (const float*)d_in[11];
  const float* bh     = (const float*)d_in[12];
  float* out = (float*)d_out;

  US* h1p = (US*)d_ws;                                   // 64*122*122*32
  US* h2p = h1p + (size_t)N_ * 122 * 122 * 32;           // 64*3600*64
  US* wt1 = h2p + (size_t)N_ * 3600 * 64;                // 3*64*96
  US* wt2 = wt1 + 3 * 64 * 96;                           // 128*64
  float* gap = (float*)(wt2 + C3_ * C2_);                // 64*128 f32

  hipMemsetAsync(gap, 0, (size_t)N_ * C3_ * sizeof(float), stream);

  {  // K0 prep: pad-zero + weight conversion
    int total = PADT + 18432 + 8192;
    k0_prep<<<(total + 255) / 256, 256, 0, stream>>>(w1, w2, h1p, wt1, wt2);
  }
  {  // K1: 30 row-chunks (4 rows each) x 64 n, 128-thread blocks
    dim3 grid(30, N_);
    k1_stem<<<grid, 128, 0, stream>>>(x, w_stem, a_stem, b_stem, h1p);
  }
  {  // K2
    dim3 grid(57, N_);
    k2_mfma<<<grid, 256, 0, stream>>>(h1p, wt1, a1, b1, h2p);
  }
  {  // K3
    dim3 grid(15, N_);
    k3_mfma<<<grid, 256, 0, stream>>>(h2p, wt2, a2, b2, gap);
  }
  {  // K4
    dim3 grid(HEAD_ / 256, N_);
    k4_head<<<grid, 256, 0, stream>>>(gap, wh, ah, bh, out);
  }
}

// Round 7
// 233.681 us; speedup vs baseline: 6.6898x; 6.6898x over previous
//
#include <hip/hip_runtime.h>

#define N_    64
#define HW_   240
#define H1_   120
#define H2_   60
#define C0_   3
#define C1_   32
#define C2_   64
#define C3_   128
#define HEAD_ 1280

typedef unsigned short US;
typedef short bf16x8 __attribute__((ext_vector_type(8)));
typedef float f32x16 __attribute__((ext_vector_type(16)));

__device__ __forceinline__ US f2bf(float f) {
  union { float f; unsigned u; } v; v.f = f;
  unsigned r = v.u + 0x7FFF + ((v.u >> 16) & 1);  // RNE
  return (US)(r >> 16);
}

// h1p padded NHWC: [n][122][122][32] bf16. interior pixel (y,x) -> [y+1][x+1].
#define H1P_ROW   (122 * 32)

// ---------------------------------------------------------------------------
// K0: prep — zero h1p pad cells; convert w1 -> wt1 [ky][oc][kx*32+ic] bf16;
// convert w2 -> wt2 [oc][ic] bf16.
// ---------------------------------------------------------------------------
#define PADN  15488           // pad elems per n
#define PADT  (64 * PADN)     // 991232
__global__ __launch_bounds__(256) void k0_prep(
    const float* __restrict__ w1, const float* __restrict__ w2,
    US* __restrict__ h1p, US* __restrict__ wt1, US* __restrict__ wt2) {
  int gid = blockIdx.x * 256 + threadIdx.x;
  if (gid < PADT) {
    int n = gid / PADN, q = gid % PADN;
    int y, x, ic;
    if (q < 7808) {            // rows 0 and 121, full width
      y = (q < 3904) ? 0 : 121;
      int r = q % 3904; x = r >> 5; ic = r & 31;
    } else {                   // cols 0 and 121, y 1..120
      int q2 = q - 7808;
      x = (q2 < 3840) ? 0 : 121;
      int r = q2 % 3840; y = 1 + (r >> 5); ic = r & 31;
    }
    h1p[(((long)n * 122 + y) * 122 + x) * 32 + ic] = 0;
  } else if (gid < PADT + 18432) {
    int e = gid - PADT;                       // w1 flat [oc][ic][ky][kx]
    int oc = e / 288, ic = (e / 9) % 32, ky = (e / 3) % 3, kx = e % 3;
    wt1[(ky * 64 + oc) * 96 + kx * 32 + ic] = f2bf(w1[e]);
  } else if (gid < PADT + 18432 + 8192) {
    int e = gid - (PADT + 18432);
    wt2[e] = f2bf(w2[e]);
  }
}

// ---------------------------------------------------------------------------
// K1: stem conv 3->32, 3x3 s2 p1, fused BN+ReLU; f32 vector math, writes
// padded NHWC bf16. Thread: 32 oc x 4 px (128 accs; compiler parks them in
// the unified AGPR file at VGPR_Count~84 — measured 66 us; do NOT split into
// 2-px passes, that spilled to scratch at 1.4 ms in R6).
// Grid (15, 64), 240/256 threads active.
// ---------------------------------------------------------------------------
__global__ __launch_bounds__(256) void k1_stem(
    const float* __restrict__ x, const float* __restrict__ w,
    const float* __restrict__ alpha, const float* __restrict__ beta,
    US* __restrict__ h1p) {
  __shared__ float wl[C1_ * C0_ * 3 * 4];  // [oc][ic][ky][kx pad4] 1152 f
  int n = blockIdx.y;
  for (int e = threadIdx.x; e < C1_ * 27; e += 256) {
    int oc = e / 27, rem = e % 27;
    int ic = rem / 9, ky = (rem / 3) % 3, kx = rem % 3;
    wl[((oc * C0_ + ic) * 3 + ky) * 4 + kx] = w[e];
  }
  __syncthreads();
  int t = threadIdx.x;
  if (t >= 240) return;
  int xg = t % 30, r = t / 30;
  int y = blockIdx.x * 8 + r;          // 15*8 = 120 exact
  int x0 = xg * 4;
  int iy0 = 2 * y - 1;
  int xA = 8 * xg;                     // 16B-aligned window start (v[1])
  int x0m = (xg == 0) ? 0 : (xA - 1);  // clamped scalar addr for v[0]
  bool xg0 = (xg == 0);

  int rofs[3]; bool yok[3];
#pragma unroll
  for (int ky = 0; ky < 3; ky++) {
    int iy = iy0 + ky;
    yok[ky] = (iy >= 0);               // upper bound never exceeded
    rofs[ky] = (iy < 0 ? 0 : iy) * HW_;
  }

  float acc[C1_][4];
#pragma unroll
  for (int o = 0; o < C1_; o++)
#pragma unroll
    for (int j = 0; j < 4; j++) acc[o][j] = 0.f;

  const float* xn = x + (long)n * C0_ * HW_ * HW_;
#pragma unroll
  for (int ic = 0; ic < C0_; ic++) {
    const float* xc = xn + ic * HW_ * HW_;
#pragma unroll
    for (int ky = 0; ky < 3; ky++) {
      const float* row = xc + rofs[ky];
      float  v0 = row[x0m];
      float4 va = *(const float4*)(row + xA);
      float4 vb = *(const float4*)(row + xA + 4);
      bool ym = yok[ky];
      float v[9];
      v[0] = (ym && !xg0) ? v0 : 0.f;
      v[1] = ym ? va.x : 0.f;  v[2] = ym ? va.y : 0.f;
      v[3] = ym ? va.z : 0.f;  v[4] = ym ? va.w : 0.f;
      v[5] = ym ? vb.x : 0.f;  v[6] = ym ? vb.y : 0.f;
      v[7] = ym ? vb.z : 0.f;  v[8] = ym ? vb.w : 0.f;
#pragma unroll
      for (int oc = 0; oc < C1_; oc++) {
        float4 wv = *(const float4*)(wl + ((oc * C0_ + ic) * 3 + ky) * 4);
#pragma unroll
        for (int j = 0; j < 4; j++) {
          acc[oc][j] = fmaf(v[2 * j],     wv.x, acc[oc][j]);
          acc[oc][j] = fmaf(v[2 * j + 1], wv.y, acc[oc][j]);
          acc[oc][j] = fmaf(v[2 * j + 2], wv.z, acc[oc][j]);
        }
      }
    }
  }
  long base = (((long)n * 122 + (y + 1)) * 122 + (x0 + 1)) * 32;
#pragma unroll
  for (int j = 0; j < 4; j++) {        // pixel
#pragma unroll
    for (int g = 0; g < 4; g++) {      // 8-channel group
      unsigned q[4];
#pragma unroll
      for (int k = 0; k < 4; k++) {
        int o = g * 8 + 2 * k;
        float v0 = fmaxf(fmaf(acc[o][j],     alpha[o],     beta[o]),     0.f);
        float v1 = fmaxf(fmaf(acc[o + 1][j], alpha[o + 1], beta[o + 1]), 0.f);
        q[k] = (unsigned)f2bf(v0) | ((unsigned)f2bf(v1) << 16);
      }
      uint4 u; u.x = q[0]; u.y = q[1]; u.z = q[2]; u.w = q[3];
      *(uint4*)(h1p + base + j * 32 + g * 8) = u;
    }
  }
}

// ---------------------------------------------------------------------------
// K2: conv 32->64 3x3 s2 via implicit-GEMM MFMA (bf16 in, f32 acc).
// Block 64px x 64oc, 4 waves (2x2). K = 3 ky-slabs of 96 contiguous (kx,ic).
// Epilogue: transpose through 8 KB LDS so global stores are full 128-B
// pixel chunks (R6 found 2-B/128-B-stride stores -> partial-sector RMW).
// Grid (57, 64).
// ---------------------------------------------------------------------------
__global__ __launch_bounds__(256) void k2_mfma(
    const US* __restrict__ h1p, const US* __restrict__ wt1,
    const float* __restrict__ alpha, const float* __restrict__ beta,
    US* __restrict__ h2p) {
  __shared__ US tile[64 * 64];  // [px_local][oc] bf16, 8 KB
  int n = blockIdx.y, tileb = blockIdx.x;
  int t = threadIdx.x, w = t >> 6, l = t & 63;
  int wm = w & 1, wn = w >> 1;
  int pxb = tileb * 64 + wm * 32;
  int lane31 = l & 31, half = l >> 5;
  int p = pxb + lane31; int pc = p < 3600 ? p : 3599;
  int y = pc / 60, xx = pc % 60;
  long abase = (((long)n * 122 + 2 * y) * 122 + 2 * xx) * 32 + half * 8;
  int oc = wn * 32 + lane31;
  const US* bbase = wt1 + oc * 96 + half * 8;

  f32x16 acc;
#pragma unroll
  for (int i = 0; i < 16; i++) acc[i] = 0.f;

#pragma unroll
  for (int ky = 0; ky < 3; ky++) {
    const US* aptr = h1p + abase + ky * H1P_ROW;
    const US* bptr = bbase + ky * (64 * 96);
#pragma unroll
    for (int s = 0; s < 6; s++) {
      bf16x8 av = *(const bf16x8*)(aptr + s * 16);
      bf16x8 bv = *(const bf16x8*)(bptr + s * 16);
      acc = __builtin_amdgcn_mfma_f32_32x32x16_bf16(av, bv, acc, 0, 0, 0);
    }
  }
  float al = alpha[oc], be = beta[oc];
#pragma unroll
  for (int r = 0; r < 16; r++) {
    int row = (r & 3) + 8 * (r >> 2) + 4 * half;
    float v = fmaxf(fmaf(acc[r], al, be), 0.f);
    tile[(wm * 32 + row) * 64 + oc] = f2bf(v);
  }
  __syncthreads();
  // store 64 px * 128 B contiguous; thread t covers 32 B (16 oc) of one px
  int e0 = t * 16;
  int pl = e0 >> 6;                 // px_local
  int pp = tileb * 64 + pl;
  if (pp < 3600) {
    uint4 u0 = *(const uint4*)(tile + e0);
    uint4 u1 = *(const uint4*)(tile + e0 + 8);
    US* dst = h2p + (long)n * 3600 * 64 + (long)pp * 64 + (e0 & 63);
    *(uint4*)dst = u0;
    *(uint4*)(dst + 8) = u1;
  }
}

// ---------------------------------------------------------------------------
// K3: pointwise 64->128 + BN + ReLU + GAP via MFMA. Wave w owns oc-tile
// 32w..32w+31; loops px tiles of 32; per-lane running sum; shfl_xor(32)
// combines halves; one atomic per oc. Grid (15, 64).
// ---------------------------------------------------------------------------
__global__ __launch_bounds__(256) void k3_mfma(
    const US* __restrict__ h2p, const US* __restrict__ wt2,
    const float* __restrict__ alpha, const float* __restrict__ beta,
    float* __restrict__ gap) {
  int n = blockIdx.y, chunk = blockIdx.x;
  int t = threadIdx.x, w = t >> 6, l = t & 63;
  int lane31 = l & 31, half = l >> 5;
  int oc = w * 32 + lane31;
  float al = alpha[oc], be = beta[oc];
  const US* bbase = wt2 + oc * 64 + half * 8;
  int t0 = chunk * 8, t1 = t0 + 8;
  if (t1 > 113) t1 = 113;
  const US* h2n = h2p + (long)n * 3600 * 64;
  float s = 0.f;
  for (int tile = t0; tile < t1; tile++) {
    int p0 = tile * 32;
    int p = p0 + lane31; int pc = p < 3600 ? p : 3599;
    const US* aptr = h2n + (long)pc * 64 + half * 8;
    f32x16 acc;
#pragma unroll
    for (int i = 0; i < 16; i++) acc[i] = 0.f;
#pragma unroll
    for (int s4 = 0; s4 < 4; s4++) {
      bf16x8 av = *(const bf16x8*)(aptr + s4 * 16);
      bf16x8 bv = *(const bf16x8*)(bbase + s4 * 16);
      acc = __builtin_amdgcn_mfma_f32_32x32x16_bf16(av, bv, acc, 0, 0, 0);
    }
    if (p0 + 31 < 3600) {
#pragma unroll
      for (int r = 0; r < 16; r++) s += fmaxf(fmaf(acc[r], al, be), 0.f);
    } else {
#pragma unroll
      for (int r = 0; r < 16; r++) {
        int row = (r & 3) + 8 * (r >> 2) + 4 * half;
        if (p0 + row < 3600) s += fmaxf(fmaf(acc[r], al, be), 0.f);
      }
    }
  }
  s += __shfl_xor(s, 32);
  if (half == 0) atomicAdd(gap + n * C3_ + oc, s);
}

// ---------------------------------------------------------------------------
// K4: head — gap/3600 @ w_head^T, BN fold + ReLU (f32).
// ---------------------------------------------------------------------------
__global__ __launch_bounds__(256) void k4_head(
    const float* __restrict__ gap, const float* __restrict__ wh,
    const float* __restrict__ alpha, const float* __restrict__ beta,
    float* __restrict__ out) {
  __shared__ float g[C3_];
  int n = blockIdx.y;
  int o = blockIdx.x * 256 + threadIdx.x;
  if (threadIdx.x < C3_)
    g[threadIdx.x] = gap[n * C3_ + threadIdx.x] * (1.f / 3600.f);
  __syncthreads();
  const float* wr = wh + (long)o * C3_;
  float acc = 0.f;
#pragma unroll 8
  for (int c = 0; c < C3_; c += 4) {
    float4 wv = *(const float4*)(wr + c);
    acc = fmaf(wv.x, g[c],     acc);
    acc = fmaf(wv.y, g[c + 1], acc);
    acc = fmaf(wv.z, g[c + 2], acc);
    acc = fmaf(wv.w, g[c + 3], acc);
  }
  out[n * HEAD_ + o] = fmaxf(fmaf(acc, alpha[o], beta[o]), 0.f);
}

// ---------------------------------------------------------------------------
extern "C" void kernel_launch(void* const* d_in, const int* in_sizes, int n_in,
                              void* d_out, int out_size, void* d_ws,
                              size_t ws_size, hipStream_t stream) {
  const float* x      = (const float*)d_in[0];
  const float* w_stem = (const float*)d_in[1];
  const float* a_stem = (const float*)d_in[2];
  const float* b_stem = (const float*)d_in[3];
  const float* w1     = (const float*)d_in[4];
  const float* a1     = (const float*)d_in[5];
  const float* b1     = (const float*)d_in[6];
  const float* w2     = (const float*)d_in[7];
  const float* a2     = (const float*)d_in[8];
  const float* b2     = (const float*)d_in[9];
  const float* wh     = (const float*)d_in[10];
  const float* ah     = (const float*)d_in[11];
  const float* bh     = (const float*)d_in[12];
  float* out = (float*)d_out;

  US* h1p = (US*)d_ws;                                   // 64*122*122*32
  US* h2p = h1p + (size_t)N_ * 122 * 122 * 32;           // 64*3600*64
  US* wt1 = h2p + (size_t)N_ * 3600 * 64;                // 3*64*96
  US* wt2 = wt1 + 3 * 64 * 96;                           // 128*64
  float* gap = (float*)(wt2 + C3_ * C2_);                // 64*128 f32

  hipMemsetAsync(gap, 0, (size_t)N_ * C3_ * sizeof(float), stream);

  {  // K0 prep: pad-zero + weight conversion
    int total = PADT + 18432 + 8192;
    k0_prep<<<(total + 255) / 256, 256, 0, stream>>>(w1, w2, h1p, wt1, wt2);
  }
  {  // K1: 15 row-chunks x 64 n
    dim3 grid(15, N_);
    k1_stem<<<grid, 256, 0, stream>>>(x, w_stem, a_stem, b_stem, h1p);
  }
  {  // K2
    dim3 grid(57, N_);
    k2_mfma<<<grid, 256, 0, stream>>>(h1p, wt1, a1, b1, h2p);
  }
  {  // K3
    dim3 grid(15, N_);
    k3_mfma<<<grid, 256, 0, stream>>>(h2p, wt2, a2, b2, gap);
  }
  {  // K4
    dim3 grid(HEAD_ / 256, N_);
    k4_head<<<grid, 256, 0, stream>>>(gap, wh, ah, bh, out);
  }
}

// Round 8
// 216.195 us; speedup vs baseline: 7.2309x; 1.0809x over previous
//
#include <hip/hip_runtime.h>

#define N_    64
#define HW_   240
#define H1_   120
#define H2_   60
#define C0_   3
#define C1_   32
#define C2_   64
#define C3_   128
#define HEAD_ 1280

typedef unsigned short US;
typedef short bf16x8 __attribute__((ext_vector_type(8)));
typedef float f32x16 __attribute__((ext_vector_type(16)));

__device__ __forceinline__ US f2bf(float f) {
  union { float f; unsigned u; } v; v.f = f;
  unsigned r = v.u + 0x7FFF + ((v.u >> 16) & 1);  // RNE
  return (US)(r >> 16);
}

// h1q parity-split padded NHWC bf16: [n][row 122][parity 2][xh 62][32ch].
// h1 pixel (gy,gx): row = gy+1; gx even=2m -> plane0[m]; gx odd=2m-1 -> plane1[m].
// Pads zeroed: rows 0,121 entirely; plane0 m=60,61; plane1 m=0,61.
// Row stride 3968 elems; plane stride 1984.
#define H1Q_ROW 3968
#define H1Q_PL  1984

// ---------------------------------------------------------------------------
// K0: prep — zero h1q pad cells; w1 -> wt1 [ky][kx][oc][ic] bf16;
// w2 -> wt2 [oc][ic] bf16; zero gap accumulator (replaces memset dispatch).
// ---------------------------------------------------------------------------
#define PADN2 23296           // pad elems per n
#define PADT2 (64 * PADN2)    // 1490944
__global__ __launch_bounds__(256) void k0_prep(
    const float* __restrict__ w1, const float* __restrict__ w2,
    US* __restrict__ h1q, US* __restrict__ wt1, US* __restrict__ wt2,
    float* __restrict__ gap) {
  int gid = blockIdx.x * 256 + threadIdx.x;
  if (gid < PADT2) {
    int n = gid / PADN2, q = gid % PADN2;
    long idx;
    if (q < 7936) {            // rows 0 and 121, both planes, full
      int y = (q < 3968) ? 0 : 121;
      int off = q % 3968;
      idx = ((long)(n * 122 + y)) * H1Q_ROW + off;
    } else {                   // rows 1..120: p0{60,61}, p1{0,61}
      int q2 = q - 7936;
      int row = q2 >> 7;       // /128
      int r = q2 & 127;
      int c = r >> 5, ic = r & 31;
      int pp = c >> 1;
      int m = (c == 0) ? 60 : (c == 1) ? 61 : (c == 2) ? 0 : 61;
      idx = ((long)(n * 122 + 1 + row)) * H1Q_ROW + pp * H1Q_PL + m * 32 + ic;
    }
    h1q[idx] = 0;
  } else if (gid < PADT2 + 18432) {
    int e = gid - PADT2;                      // w1 flat [oc][ic][ky][kx]
    int oc = e / 288, ic = (e / 9) % 32, ky = (e / 3) % 3, kx = e % 3;
    wt1[((ky * 3 + kx) * 64 + oc) * 32 + ic] = f2bf(w1[e]);
  } else if (gid < PADT2 + 18432 + 8192) {
    int e = gid - (PADT2 + 18432);
    wt2[e] = f2bf(w2[e]);
  } else if (gid < PADT2 + 18432 + 8192 + 8192) {
    gap[gid - (PADT2 + 18432 + 8192)] = 0.f;
  }
}

// ---------------------------------------------------------------------------
// K1: stem conv 3->32, 3x3 s2 p1, fused BN+ReLU; f32 vector math, writes
// parity-split padded NHWC bf16. Thread: 32 oc x 4 px (128 accs; compiler
// parks them in unified AGPR file at VGPR~84 — 66 us. Do NOT split into 2-px
// passes: R6 showed that spills to scratch at 1.4 ms).
// Grid (15, 64), 240/256 threads active.
// ---------------------------------------------------------------------------
__global__ __launch_bounds__(256) void k1_stem(
    const float* __restrict__ x, const float* __restrict__ w,
    const float* __restrict__ alpha, const float* __restrict__ beta,
    US* __restrict__ h1q) {
  __shared__ float wl[C1_ * C0_ * 3 * 4];  // [oc][ic][ky][kx pad4] 1152 f
  int n = blockIdx.y;
  for (int e = threadIdx.x; e < C1_ * 27; e += 256) {
    int oc = e / 27, rem = e % 27;
    int ic = rem / 9, ky = (rem / 3) % 3, kx = rem % 3;
    wl[((oc * C0_ + ic) * 3 + ky) * 4 + kx] = w[e];
  }
  __syncthreads();
  int t = threadIdx.x;
  if (t >= 240) return;
  int xg = t % 30, r = t / 30;
  int y = blockIdx.x * 8 + r;          // 15*8 = 120 exact
  int iy0 = 2 * y - 1;
  int xA = 8 * xg;                     // 16B-aligned window start (v[1])
  int x0m = (xg == 0) ? 0 : (xA - 1);  // clamped scalar addr for v[0]
  bool xg0 = (xg == 0);

  int rofs[3]; bool yok[3];
#pragma unroll
  for (int ky = 0; ky < 3; ky++) {
    int iy = iy0 + ky;
    yok[ky] = (iy >= 0);
    rofs[ky] = (iy < 0 ? 0 : iy) * HW_;
  }

  float acc[C1_][4];
#pragma unroll
  for (int o = 0; o < C1_; o++)
#pragma unroll
    for (int j = 0; j < 4; j++) acc[o][j] = 0.f;

  const float* xn = x + (long)n * C0_ * HW_ * HW_;
#pragma unroll
  for (int ic = 0; ic < C0_; ic++) {
    const float* xc = xn + ic * HW_ * HW_;
#pragma unroll
    for (int ky = 0; ky < 3; ky++) {
      const float* row = xc + rofs[ky];
      float  v0 = row[x0m];
      float4 va = *(const float4*)(row + xA);
      float4 vb = *(const float4*)(row + xA + 4);
      bool ym = yok[ky];
      float v[9];
      v[0] = (ym && !xg0) ? v0 : 0.f;
      v[1] = ym ? va.x : 0.f;  v[2] = ym ? va.y : 0.f;
      v[3] = ym ? va.z : 0.f;  v[4] = ym ? va.w : 0.f;
      v[5] = ym ? vb.x : 0.f;  v[6] = ym ? vb.y : 0.f;
      v[7] = ym ? vb.z : 0.f;  v[8] = ym ? vb.w : 0.f;
#pragma unroll
      for (int oc = 0; oc < C1_; oc++) {
        float4 wv = *(const float4*)(wl + ((oc * C0_ + ic) * 3 + ky) * 4);
#pragma unroll
        for (int j = 0; j < 4; j++) {
          acc[oc][j] = fmaf(v[2 * j],     wv.x, acc[oc][j]);
          acc[oc][j] = fmaf(v[2 * j + 1], wv.y, acc[oc][j]);
          acc[oc][j] = fmaf(v[2 * j + 2], wv.z, acc[oc][j]);
        }
      }
    }
  }
  // parity-split store: gx = 4xg+j; j0->p0 m=2xg, j1->p1 m=2xg+1,
  // j2->p0 m=2xg+1, j3->p1 m=2xg+2. Full 64-B chunks.
  long rowb = ((long)(n * 122 + y + 1)) * H1Q_ROW;
  long adr[4];
  adr[0] = rowb + (long)(2 * xg) * 32;
  adr[1] = rowb + H1Q_PL + (long)(2 * xg + 1) * 32;
  adr[2] = rowb + (long)(2 * xg + 1) * 32;
  adr[3] = rowb + H1Q_PL + (long)(2 * xg + 2) * 32;
#pragma unroll
  for (int j = 0; j < 4; j++) {
#pragma unroll
    for (int g = 0; g < 4; g++) {
      unsigned q[4];
#pragma unroll
      for (int k = 0; k < 4; k++) {
        int o = g * 8 + 2 * k;
        float v0 = fmaxf(fmaf(acc[o][j],     alpha[o],     beta[o]),     0.f);
        float v1 = fmaxf(fmaf(acc[o + 1][j], alpha[o + 1], beta[o + 1]), 0.f);
        q[k] = (unsigned)f2bf(v0) | ((unsigned)f2bf(v1) << 16);
      }
      uint4 u; u.x = q[0]; u.y = q[1]; u.z = q[2]; u.w = q[3];
      *(uint4*)(h1q + adr[j] + g * 8) = u;
    }
  }
}

// ---------------------------------------------------------------------------
// K2: conv 32->64 3x3 s2 via implicit-GEMM MFMA (bf16 in, f32 acc).
// Parity-split h1q makes every A-load coalesced: per (ky,kx) tap, lanes
// 0..31 read consecutive 64-B chunks (kx parity selects the plane).
// K = 9 taps x 2 MFMA(K=16). Epilogue via LDS -> full 128-B pixel stores.
// Grid (57, 64).
// ---------------------------------------------------------------------------
__global__ __launch_bounds__(256) void k2_mfma(
    const US* __restrict__ h1q, const US* __restrict__ wt1,
    const float* __restrict__ alpha, const float* __restrict__ beta,
    US* __restrict__ h2p) {
  __shared__ US tile[64 * 64];  // [px_local][oc] bf16, 8 KB
  int n = blockIdx.y, tileb = blockIdx.x;
  int t = threadIdx.x, w = t >> 6, l = t & 63;
  int wm = w & 1, wn = w >> 1;
  int pxb = tileb * 64 + wm * 32;
  int lane31 = l & 31, half = l >> 5;
  int p = pxb + lane31; int pc = p < 3600 ? p : 3599;
  int y = pc / 60, xx = pc % 60;
  int oc = wn * 32 + lane31;

  f32x16 acc;
#pragma unroll
  for (int i = 0; i < 16; i++) acc[i] = 0.f;

#pragma unroll
  for (int ky = 0; ky < 3; ky++) {
    // padded row index = 2y + ky; base at plane0 m=xx (+half's 8-ic offset)
    const US* a1 = h1q + ((long)(n * 122 + 2 * y + ky)) * H1Q_ROW
                       + (long)xx * 32 + half * 8;      // kx=1: p0, m=xx
    const US* a0 = a1 + H1Q_PL;                         // kx=0: p1, m=xx
    const US* a2 = a1 + H1Q_PL + 32;                    // kx=2: p1, m=xx+1
    const US* aps[3] = {a0, a1, a2};
    const US* wk = wt1 + (ky * 3) * (64 * 32) + oc * 32 + half * 8;
#pragma unroll
    for (int kx = 0; kx < 3; kx++) {
      const US* ap = aps[kx];
      const US* bp = wk + kx * (64 * 32);
#pragma unroll
      for (int c = 0; c < 2; c++) {
        bf16x8 av = *(const bf16x8*)(ap + c * 16);
        bf16x8 bv = *(const bf16x8*)(bp + c * 16);
        acc = __builtin_amdgcn_mfma_f32_32x32x16_bf16(av, bv, acc, 0, 0, 0);
      }
    }
  }
  float al = alpha[oc], be = beta[oc];
#pragma unroll
  for (int r = 0; r < 16; r++) {
    int row = (r & 3) + 8 * (r >> 2) + 4 * half;
    float v = fmaxf(fmaf(acc[r], al, be), 0.f);
    tile[(wm * 32 + row) * 64 + oc] = f2bf(v);
  }
  __syncthreads();
  // store 64 px * 128 B contiguous; thread t covers 32 B (16 oc) of one px
  int e0 = t * 16;
  int pl = e0 >> 6;
  int pp = tileb * 64 + pl;
  if (pp < 3600) {
    uint4 u0 = *(const uint4*)(tile + e0);
    uint4 u1 = *(const uint4*)(tile + e0 + 8);
    US* dst = h2p + (long)n * 3600 * 64 + (long)pp * 64 + (e0 & 63);
    *(uint4*)dst = u0;
    *(uint4*)(dst + 8) = u1;
  }
}

// ---------------------------------------------------------------------------
// K3: pointwise 64->128 + BN + ReLU + GAP via MFMA. Wave w owns oc-tile
// 32w..32w+31; loops px tiles of 32; per-lane running sum; shfl_xor(32)
// combines halves; one atomic per oc. Grid (15, 64).
// ---------------------------------------------------------------------------
__global__ __launch_bounds__(256) void k3_mfma(
    const US* __restrict__ h2p, const US* __restrict__ wt2,
    const float* __restrict__ alpha, const float* __restrict__ beta,
    float* __restrict__ gap) {
  int n = blockIdx.y, chunk = blockIdx.x;
  int t = threadIdx.x, w = t >> 6, l = t & 63;
  int lane31 = l & 31, half = l >> 5;
  int oc = w * 32 + lane31;
  float al = alpha[oc], be = beta[oc];
  const US* bbase = wt2 + oc * 64 + half * 8;
  int t0 = chunk * 8, t1 = t0 + 8;
  if (t1 > 113) t1 = 113;
  const US* h2n = h2p + (long)n * 3600 * 64;
  float s = 0.f;
  for (int tile = t0; tile < t1; tile++) {
    int p0 = tile * 32;
    int p = p0 + lane31; int pc = p < 3600 ? p : 3599;
    const US* aptr = h2n + (long)pc * 64 + half * 8;
    f32x16 acc;
#pragma unroll
    for (int i = 0; i < 16; i++) acc[i] = 0.f;
#pragma unroll
    for (int s4 = 0; s4 < 4; s4++) {
      bf16x8 av = *(const bf16x8*)(aptr + s4 * 16);
      bf16x8 bv = *(const bf16x8*)(bbase + s4 * 16);
      acc = __builtin_amdgcn_mfma_f32_32x32x16_bf16(av, bv, acc, 0, 0, 0);
    }
    if (p0 + 31 < 3600) {
#pragma unroll
      for (int r = 0; r < 16; r++) s += fmaxf(fmaf(acc[r], al, be), 0.f);
    } else {
#pragma unroll
      for (int r = 0; r < 16; r++) {
        int row = (r & 3) + 8 * (r >> 2) + 4 * half;
        if (p0 + row < 3600) s += fmaxf(fmaf(acc[r], al, be), 0.f);
      }
    }
  }
  s += __shfl_xor(s, 32);
  if (half == 0) atomicAdd(gap + n * C3_ + oc, s);
}

// ---------------------------------------------------------------------------
// K4: head — gap/3600 @ w_head^T, BN fold + ReLU (f32).
// ---------------------------------------------------------------------------
__global__ __launch_bounds__(256) void k4_head(
    const float* __restrict__ gap, const float* __restrict__ wh,
    const float* __restrict__ alpha, const float* __restrict__ beta,
    float* __restrict__ out) {
  __shared__ float g[C3_];
  int n = blockIdx.y;
  int o = blockIdx.x * 256 + threadIdx.x;
  if (threadIdx.x < C3_)
    g[threadIdx.x] = gap[n * C3_ + threadIdx.x] * (1.f / 3600.f);
  __syncthreads();
  const float* wr = wh + (long)o * C3_;
  float acc = 0.f;
#pragma unroll 8
  for (int c = 0; c < C3_; c += 4) {
    float4 wv = *(const float4*)(wr + c);
    acc = fmaf(wv.x, g[c],     acc);
    acc = fmaf(wv.y, g[c + 1], acc);
    acc = fmaf(wv.z, g[c + 2], acc);
    acc = fmaf(wv.w, g[c + 3], acc);
  }
  out[n * HEAD_ + o] = fmaxf(fmaf(acc, alpha[o], beta[o]), 0.f);
}

// ---------------------------------------------------------------------------
extern "C" void kernel_launch(void* const* d_in, const int* in_sizes, int n_in,
                              void* d_out, int out_size, void* d_ws,
                              size_t ws_size, hipStream_t stream) {
  const float* x      = (const float*)d_in[0];
  const float* w_stem = (const float*)d_in[1];
  const float* a_stem = (const float*)d_in[2];
  const float* b_stem = (const float*)d_in[3];
  const float* w1     = (const float*)d_in[4];
  const float* a1     = (const float*)d_in[5];
  const float* b1     = (const float*)d_in[6];
  const float* w2     = (const float*)d_in[7];
  const float* a2     = (const float*)d_in[8];
  const float* b2     = (const float*)d_in[9];
  const float* wh     = (const float*)d_in[10];
  const float* ah     = (const float*)d_in[11];
  const float* bh     = (const float*)d_in[12];
  float* out = (float*)d_out;

  US* h1q = (US*)d_ws;                                   // 64*122*3968
  US* h2p = h1q + (size_t)N_ * 122 * H1Q_ROW;            // 64*3600*64
  US* wt1 = h2p + (size_t)N_ * 3600 * 64;                // 9*64*32
  US* wt2 = wt1 + 9 * 64 * 32;                           // 128*64
  float* gap = (float*)(wt2 + C3_ * C2_);                // 64*128 f32

  {  // K0 prep: pad-zero + weight conversion + gap zero
    int total = PADT2 + 18432 + 8192 + 8192;
    k0_prep<<<(total + 255) / 256, 256, 0, stream>>>(w1, w2, h1q, wt1, wt2,
                                                     gap);
  }
  {  // K1: 15 row-chunks x 64 n
    dim3 grid(15, N_);
    k1_stem<<<grid, 256, 0, stream>>>(x, w_stem, a_stem, b_stem, h1q);
  }
  {  // K2
    dim3 grid(57, N_);
    k2_mfma<<<grid, 256, 0, stream>>>(h1q, wt1, a1, b1, h2p);
  }
  {  // K3
    dim3 grid(15, N_);
    k3_mfma<<<grid, 256, 0, stream>>>(h2p, wt2, a2, b2, gap);
  }
  {  // K4
    dim3 grid(HEAD_ / 256, N_);
    k4_head<<<grid, 256, 0, stream>>>(gap, wh, ah, bh, out);
  }
}